// Round 15
// baseline (391.725 us; speedup 1.0000x reference)
//
#include <hip/hip_runtime.h>
#include <hip/hip_bf16.h>
#include <cstdint>

typedef unsigned short u16;
typedef unsigned int u32;
typedef short s16x8 __attribute__((ext_vector_type(8)));
typedef float f32x4 __attribute__((ext_vector_type(4)));

// Problem constants (B=4, T=2048, D=1024, E=8, H=2048, K=2)
constexpr int NTOK = 8192;
constexpr int DDIM = 1024;
constexpr int NEXP = 8;
constexpr int HDIM = 2048;
constexpr int NPAIR = NTOK * 2;   // 16384

// d_out layout (floats), concatenated tuple
constexpr size_t OFF_OUT   = 0;
constexpr size_t OFF_AUX   = 8388608;
constexpr size_t OFF_PROBS = 8388609;
constexpr size_t OFF_TIDX  = 8454145;
constexpr size_t OFF_TPR   = 8470529;

// workspace layout (bytes)
constexpr size_t WS_CNT  = 0;          // 8 int
constexpr size_t WS_PSUM = 32;         // 8 float
constexpr size_t WS_BASE = 64;         // 8 int
constexpr size_t WS_IDS  = 1024;       // 8*8192 int   -> ends 263168
constexpr size_t WS_PRW  = 263168;     // 8*8192 float -> ends 525312
constexpr size_t WS_W1T  = 17302528;   // 8*2048*1024 bf16 (transposed [E][H][D])
constexpr size_t WS_W2T  = 50856960;   // 8*1024*2048 bf16 (transposed [E][D][H])
constexpr size_t WS_H    = 84411392;   // 16384*2048 bf16
constexpr size_t WS_XG   = 151520256;  // 16384*1024 bf16 (gathered A rows)
constexpr size_t WS_NEED = 185074688;

__device__ __forceinline__ u16 f2b(float f) {
  u32 u = __float_as_uint(f);
  u32 r = (u + 0x7fffu + ((u >> 16) & 1u)) >> 16;
  return (u16)r;
}

typedef const uint32_t __attribute__((address_space(1)))* gptr_t;
typedef uint32_t __attribute__((address_space(3)))* lptr_t;

__device__ __forceinline__ void gload16(const void* gp, void* lp) {
  __builtin_amdgcn_global_load_lds((gptr_t)gp, (lptr_t)(uintptr_t)lp, 16, 0, 0);
}

// ------------- transpose + convert, both weights in ONE dispatch -------------
__global__ __launch_bounds__(256) void tconv_all_kernel(
    const float* __restrict__ w1, u16* __restrict__ w1t,
    const float* __restrict__ w2, u16* __restrict__ w2t) {
  int id = blockIdx.x;
  const float* in;
  u16* out;
  int R, C, e, r;
  if (id < 4096) {
    in = w1; out = w1t; R = DDIM; C = HDIM;
    e = id >> 9; r = id & 511;
  } else {
    id -= 4096;
    in = w2; out = w2t; R = HDIM; C = DDIM;
    e = id >> 9; r = id & 511;
  }
  int xt = (R == DDIM) ? (r & 31) : (r & 15);
  int yt = (R == DDIM) ? (r >> 5) : (r >> 4);
  int c0 = xt * 64, r0 = yt * 64;

  __shared__ float tile[64][65];
  int tx = threadIdx.x & 15, ty = threadIdx.x >> 4;
  const float* src = in + (size_t)e * R * C;
#pragma unroll
  for (int i = 0; i < 4; ++i) {
    int rr = ty + i * 16;
    float4 v = *(const float4*)(src + (size_t)(r0 + rr) * C + c0 + tx * 4);
    tile[rr][tx * 4 + 0] = v.x; tile[rr][tx * 4 + 1] = v.y;
    tile[rr][tx * 4 + 2] = v.z; tile[rr][tx * 4 + 3] = v.w;
  }
  __syncthreads();
  u16* dst = out + (size_t)e * R * C;
#pragma unroll
  for (int i = 0; i < 4; ++i) {
    int c = ty + i * 16;
    ushort4 o;
    o.x = f2b(tile[tx * 4 + 0][c]); o.y = f2b(tile[tx * 4 + 1][c]);
    o.z = f2b(tile[tx * 4 + 2][c]); o.w = f2b(tile[tx * 4 + 3][c]);
    *(ushort4*)(dst + (size_t)(c0 + c) * R + r0 + tx * 4) = o;
  }
}

// ---------------- router ----------------
__global__ __launch_bounds__(256) void router_kernel(
    const float* __restrict__ x, const float* __restrict__ gw,
    float* __restrict__ outbuf,
    int* __restrict__ cnt, float* __restrict__ psum,
    int* __restrict__ ids, float* __restrict__ prw) {
  __shared__ float gwl[DDIM * NEXP];
  __shared__ int lcnt[NEXP];
  __shared__ float psl[NEXP];
  __shared__ int gbl[NEXP];

  const int tid = threadIdx.x;
#pragma unroll
  for (int k = 0; k < 8; ++k)
    ((float4*)gwl)[tid + k * 256] = ((const float4*)gw)[tid + k * 256];
  if (tid < NEXP) { lcnt[tid] = 0; psl[tid] = 0.f; }
  __syncthreads();

  const int tloc = tid >> 2, part = tid & 3;
  const int t = blockIdx.x * 64 + tloc;
  double acc[NEXP];
#pragma unroll
  for (int e = 0; e < NEXP; ++e) acc[e] = 0.0;

  const float* xrow = x + (size_t)t * DDIM + part * 256;
  for (int i = 0; i < 64; ++i) {
    float4 v = ((const float4*)xrow)[i];
    const float* g = &gwl[(part * 256 + i * 4) * NEXP];
#pragma unroll
    for (int j = 0; j < 4; ++j) {
      double xs = (double)((const float*)&v)[j];
#pragma unroll
      for (int e = 0; e < NEXP; ++e) acc[e] += xs * (double)g[j * NEXP + e];
    }
  }
#pragma unroll
  for (int e = 0; e < NEXP; ++e) {
    acc[e] += __shfl_xor(acc[e], 1);
    acc[e] += __shfl_xor(acc[e], 2);
  }

  int e0 = 0, e1 = 0, lp0 = 0, lp1 = 0;
  float tp0 = 0.f, tp1 = 0.f;
  if (part == 0) {
    float l[NEXP];
#pragma unroll
    for (int e = 0; e < NEXP; ++e) l[e] = (float)acc[e];
    float m = l[0];
#pragma unroll
    for (int e = 1; e < NEXP; ++e) m = fmaxf(m, l[e]);
    float p[NEXP], s = 0.f;
#pragma unroll
    for (int e = 0; e < NEXP; ++e) { p[e] = expf(l[e] - m); s += p[e]; }
    float inv = 1.0f / s;
#pragma unroll
    for (int e = 0; e < NEXP; ++e) {
      p[e] *= inv;
      outbuf[OFF_PROBS + (size_t)t * NEXP + e] = p[e];
      atomicAdd(&psl[e], p[e]);
    }
#pragma unroll
    for (int e = 1; e < NEXP; ++e) if (p[e] > p[e0]) e0 = e;
    e1 = -1;
#pragma unroll
    for (int e = 0; e < NEXP; ++e)
      if (e != e0 && (e1 < 0 || p[e] > p[e1])) e1 = e;
    float ps = p[e0] + p[e1];
    tp0 = p[e0] / ps;
    tp1 = p[e1] / ps;
    outbuf[OFF_TIDX + t * 2 + 0] = (float)e0;
    outbuf[OFF_TIDX + t * 2 + 1] = (float)e1;
    outbuf[OFF_TPR + t * 2 + 0] = tp0;
    outbuf[OFF_TPR + t * 2 + 1] = tp1;
    lp0 = atomicAdd(&lcnt[e0], 1);
    lp1 = atomicAdd(&lcnt[e1], 1);
  }
  __syncthreads();
  if (tid < NEXP) {
    gbl[tid] = atomicAdd(&cnt[tid], lcnt[tid]);
    atomicAdd(&psum[tid], psl[tid]);
  }
  __syncthreads();
  if (part == 0) {
    int pos0 = gbl[e0] + lp0;
    int pos1 = gbl[e1] + lp1;
    ids[e0 * NTOK + pos0] = t;
    ids[e1 * NTOK + pos1] = t;
    prw[e0 * NTOK + pos0] = tp0;
    prw[e1 * NTOK + pos1] = tp1;
  }
}

// ---------------- bases + aux loss ----------------
__global__ void finalize_kernel(const int* __restrict__ cnt,
                                const float* __restrict__ psum,
                                int* __restrict__ base, float* __restrict__ outbuf) {
  if (threadIdx.x == 0 && blockIdx.x == 0) {
    int b = 0;
    float aux = 0.f;
    for (int e = 0; e < NEXP; ++e) {
      base[e] = b;
      b += cnt[e];
      aux += (float)cnt[e] * psum[e];
    }
    outbuf[OFF_AUX] = aux * (float)NEXP / ((float)NTOK * (float)NTOK);
  }
}

// ------- gather + convert -------
__global__ __launch_bounds__(256) void gather_kernel(
    const float* __restrict__ x, u16* __restrict__ xg,
    const int* __restrict__ cnt, const int* __restrict__ base,
    const int* __restrict__ ids) {
  const int e = blockIdx.y;
  const int cnte = cnt[e];
  const int lane = threadIdx.x & 31;
  const int rgrp = threadIdx.x >> 5;
#pragma unroll
  for (int p = 0; p < 8; ++p) {
    int pos = blockIdx.x * 64 + p * 8 + rgrp;
    if (pos < cnte) {
      int tok = ids[e * NTOK + pos];
      const float4* src = (const float4*)(x + (size_t)tok * DDIM);
      ushort4* dst = (ushort4*)(xg + (size_t)(base[e] + pos) * DDIM);
#pragma unroll
      for (int pp = 0; pp < 8; ++pp) {
        float4 v = src[pp * 32 + lane];
        ushort4 o;
        o.x = f2b(v.x); o.y = f2b(v.y); o.z = f2b(v.z); o.w = f2b(v.w);
        dst[pp * 32 + lane] = o;
      }
    }
  }
}

// -------- grouped GEMM: 256x256 tile, BK=64, 8 waves, 8-PHASE schedule (m201-style) --------
// 2 K-tiles/iter in 2 LDS dbufs. Per K-tile 4 phases, each {stage? ; ds_read frags ;
// barrier ; setprio MFMA x16 ; barrier}. Stage schedule (region-liveness audited):
//   P1: A(t+1)->buf1   (buf1-A last read prev P8)
//   P4: B(t+2)->buf0   (buf0-B last read P3) ; vmcnt(4) before closing barrier
//   P5: A(t+2)->buf0   (buf0-A last read P4)
//   P8: B(t+3)->buf1   (buf1-B last read P7) ; vmcnt(4) before closing barrier
// vmcnt(4) leaves only the newest 4 loads (one B half-pair) in flight -> tile for the
// NEXT half is guaranteed landed; never drains to 0 mid-loop (T4).
// Swizzle: chunk c = cp ^ (row&7) both-sides (R7-verified conflict-free at BK=64).
template <int MODE>
__global__ __launch_bounds__(512, 2) void moe_gemm_kernel(
    const u16* __restrict__ Asrc, const u16* __restrict__ Bt,
    u16* __restrict__ hout, float* __restrict__ yout,
    const int* __restrict__ cnt, const int* __restrict__ base,
    const int* __restrict__ ids, const float* __restrict__ prw) {
  constexpr int KDIM = (MODE == 0) ? 1024 : 2048;
  constexpr int NDIM = (MODE == 0) ? 2048 : 1024;
  constexpr int NT2 = KDIM / 64;    // K-tiles
  constexpr int NITER = NT2 / 2;    // 2 K-tiles per iter
  constexpr int NB = NDIM / 256;
  constexpr int MGRP = 2, QPG = MGRP * NB;
  const int wgid = blockIdx.x;
  const int e = wgid & 7;           // expert -> XCD lane
  const int q = wgid >> 3;
  const int mg = q / QPG;
  const int rr_ = q % QPG;
  const int m0 = (mg * MGRP + (rr_ % MGRP)) * 256;
  const int n0 = (rr_ / MGRP) * 256;
  const int cnte = cnt[e];
  if (m0 >= cnte) return;
  const int gbase = base[e];

  __shared__ u16 Al[2][256 * 64];  // 64 KB
  __shared__ u16 Bl[2][256 * 64];  // 64 KB

  const int tid = threadIdx.x;
  const int lane = tid & 63, wid = tid >> 6;
  const int wm = (wid >> 2) * 128, wn = (wid & 3) * 64;  // 2M x 4N waves
  const int r15 = lane & 15, l4 = lane >> 4;

  // staging precompute: half h (128 rows), qq in {0,1}: j = qq*512+tid,
  // row128 = j>>3, cp = j&7, global chunk c = cp ^ (row&7). LDS dest is LINEAR
  // (= j*16 bytes within the half) as global_load_lds requires.
  const char* aS[2][2];
  const char* bS[2][2];
  u32 dIx[2][2];
#pragma unroll
  for (int h = 0; h < 2; ++h) {
#pragma unroll
    for (int qq = 0; qq < 2; ++qq) {
      int j = qq * 512 + tid;
      int row128 = j >> 3;
      int cp = j & 7;
      int c = cp ^ (row128 & 7);
      int row = h * 128 + row128;
      int gr = gbase + m0 + row;
      if (gr > NPAIR - 1) gr = NPAIR - 1;
      aS[h][qq] = (const char*)Asrc + ((size_t)gr * KDIM + (size_t)c * 8) * 2;
      size_t nrow = (size_t)e * NDIM + n0 + row;
      bS[h][qq] = (const char*)Bt + (nrow * KDIM + (size_t)c * 8) * 2;
      dIx[h][qq] = (u32)(row * 64 + cp * 8);
    }
  }

  f32x4 acc[8][4];
#pragma unroll
  for (int i = 0; i < 8; ++i)
#pragma unroll
    for (int jn = 0; jn < 4; ++jn) acc[i][jn] = (f32x4){0.f, 0.f, 0.f, 0.f};

#define STA(bf_, kt_)                                                      \
  do {                                                                     \
    _Pragma("unroll") for (int h = 0; h < 2; ++h)                          \
      _Pragma("unroll") for (int qq = 0; qq < 2; ++qq)                     \
        gload16(aS[h][qq] + (size_t)(kt_) * 128, (void*)&Al[bf_][dIx[h][qq]]); \
  } while (0)
#define STB(bf_, kt_)                                                      \
  do {                                                                     \
    _Pragma("unroll") for (int h = 0; h < 2; ++h)                          \
      _Pragma("unroll") for (int qq = 0; qq < 2; ++qq)                     \
        gload16(bS[h][qq] + (size_t)(kt_) * 128, (void*)&Bl[bf_][dIx[h][qq]]); \
  } while (0)
#define BAR __builtin_amdgcn_s_barrier()

  s16x8 afr[4], bfr[4];
#define RDA(Av_, mi_, kk_)                                                  \
  { int row = wm + (mi_) * 16 + r15;                                        \
    afr[(mi_) & 3] = (Av_)[row * 8 + (((kk_) * 4 + l4) ^ (row & 7))]; }
#define RDB(Bv_, ni_, kk_)                                                  \
  { int row = wn + (ni_) * 16 + r15;                                        \
    bfr[ni_] = (Bv_)[row * 8 + (((kk_) * 4 + l4) ^ (row & 7))]; }
#define MM16(ML)                                                            \
  do {                                                                      \
    __builtin_amdgcn_s_setprio(1);                                          \
    _Pragma("unroll") for (int mi = 0; mi < 4; ++mi)                        \
      _Pragma("unroll") for (int ni = 0; ni < 4; ++ni)                      \
        acc[(ML) + mi][ni] = __builtin_amdgcn_mfma_f32_16x16x32_bf16(       \
            afr[mi], bfr[ni], acc[(ML) + mi][ni], 0, 0, 0);                 \
    __builtin_amdgcn_s_setprio(0);                                          \
  } while (0)

  const s16x8* Av0 = (const s16x8*)Al[0];
  const s16x8* Bv0 = (const s16x8*)Bl[0];
  const s16x8* Av1 = (const s16x8*)Al[1];
  const s16x8* Bv1 = (const s16x8*)Bl[1];

  // prologue: tile0 A+B -> buf0, tile1 B -> buf1 (12 loads/thread); confirm tile0.
  STA(0, 0); STB(0, 0); STB(1, 1);
  asm volatile("s_waitcnt vmcnt(4)" ::: "memory");  // tile0 landed; tile1-B in flight
  BAR;

  for (int it = 0; it < NITER; ++it) {
    const bool last = (it == NITER - 1);
    const int t0 = 2 * it;
    // ======== K-tile t0 in buf0 ========
    // P1: stage A(t0+1)->buf1 ; read kk0 frags ; MFMA mi0-3
    STA(1, t0 + 1);
    RDB(Bv0, 0, 0); RDB(Bv0, 1, 0); RDB(Bv0, 2, 0); RDB(Bv0, 3, 0);
    RDA(Av0, 0, 0); RDA(Av0, 1, 0); RDA(Av0, 2, 0); RDA(Av0, 3, 0);
    BAR; MM16(0); BAR;
    // P2: MFMA mi4-7 kk0
    RDA(Av0, 4, 0); RDA(Av0, 5, 0); RDA(Av0, 6, 0); RDA(Av0, 7, 0);
    BAR; MM16(4); BAR;
    // P3: kk1 frags ; MFMA mi0-3
    RDB(Bv0, 0, 1); RDB(Bv0, 1, 1); RDB(Bv0, 2, 1); RDB(Bv0, 3, 1);
    RDA(Av0, 0, 1); RDA(Av0, 1, 1); RDA(Av0, 2, 1); RDA(Av0, 3, 1);
    BAR; MM16(0); BAR;
    // P4: stage B(t0+2)->buf0 ; MFMA mi4-7 kk1 ; vmcnt ; barrier
    if (!last) STB(0, t0 + 2);
    RDA(Av0, 4, 1); RDA(Av0, 5, 1); RDA(Av0, 6, 1); RDA(Av0, 7, 1);
    BAR; MM16(4);
    if (last) asm volatile("s_waitcnt vmcnt(0)" ::: "memory");
    else      asm volatile("s_waitcnt vmcnt(4)" ::: "memory");
    BAR;
    // ======== K-tile t0+1 in buf1 ========
    // P5: stage A(t0+2)->buf0 ; read kk0 ; MFMA mi0-3
    if (!last) STA(0, t0 + 2);
    RDB(Bv1, 0, 0); RDB(Bv1, 1, 0); RDB(Bv1, 2, 0); RDB(Bv1, 3, 0);
    RDA(Av1, 0, 0); RDA(Av1, 1, 0); RDA(Av1, 2, 0); RDA(Av1, 3, 0);
    BAR; MM16(0); BAR;
    // P6
    RDA(Av1, 4, 0); RDA(Av1, 5, 0); RDA(Av1, 6, 0); RDA(Av1, 7, 0);
    BAR; MM16(4); BAR;
    // P7
    RDB(Bv1, 0, 1); RDB(Bv1, 1, 1); RDB(Bv1, 2, 1); RDB(Bv1, 3, 1);
    RDA(Av1, 0, 1); RDA(Av1, 1, 1); RDA(Av1, 2, 1); RDA(Av1, 3, 1);
    BAR; MM16(0); BAR;
    // P8: stage B(t0+3)->buf1 ; MFMA mi4-7 kk1 ; vmcnt ; barrier
    if (!last) STB(1, t0 + 3);
    RDA(Av1, 4, 1); RDA(Av1, 5, 1); RDA(Av1, 6, 1); RDA(Av1, 7, 1);
    BAR; MM16(4);
    if (!last) asm volatile("s_waitcnt vmcnt(4)" ::: "memory");
    BAR;
  }
#undef STA
#undef STB
#undef BAR
#undef RDA
#undef RDB
#undef MM16

  // epilogue: C/D layout col = lane&15, row = (lane>>4)*4 + j
#pragma unroll
  for (int mi = 0; mi < 8; ++mi) {
#pragma unroll
    for (int jr = 0; jr < 4; ++jr) {
      int rl = wm + mi * 16 + l4 * 4 + jr;
      if (m0 + rl < cnte) {
        if (MODE == 0) {
          size_t grow = (size_t)(gbase + m0 + rl);
#pragma unroll
          for (int ni = 0; ni < 4; ++ni) {
            float v = acc[mi][ni][jr];
            v = 0.5f * v * (1.0f + erff(v * 0.70710678118654752f));
            int col = n0 + wn + ni * 16 + r15;
            hout[grow * NDIM + col] = f2b(v);
          }
        } else {
          int tok = ids[e * NTOK + m0 + rl];
          float p = prw[e * NTOK + m0 + rl];
#pragma unroll
          for (int ni = 0; ni < 4; ++ni) {
            int col = n0 + wn + ni * 16 + r15;
            atomicAdd(&yout[(size_t)tok * DDIM + col], p * acc[mi][ni][jr]);
          }
        }
      }
    }
  }
}

extern "C" void kernel_launch(void* const* d_in, const int* in_sizes, int n_in,
                              void* d_out, int out_size, void* d_ws, size_t ws_size,
                              hipStream_t stream) {
  const float* x = (const float*)d_in[0];
  const float* gw = (const float*)d_in[1];
  const float* w1 = (const float*)d_in[2];
  const float* w2 = (const float*)d_in[3];
  float* out = (float*)d_out;
  char* w = (char*)d_ws;
  if (ws_size < WS_NEED) return;  // insufficient workspace -> loud failure

  int* cnt = (int*)(w + WS_CNT);
  float* psum = (float*)(w + WS_PSUM);
  int* base = (int*)(w + WS_BASE);
  int* ids = (int*)(w + WS_IDS);
  float* prw = (float*)(w + WS_PRW);
  u16* w1t = (u16*)(w + WS_W1T);
  u16* w2t = (u16*)(w + WS_W2T);
  u16* hbuf = (u16*)(w + WS_H);
  u16* xg = (u16*)(w + WS_XG);

  (void)hipMemsetAsync(w, 0, 96, stream);
  (void)hipMemsetAsync(out + OFF_OUT, 0, (size_t)NTOK * DDIM * sizeof(float), stream);
  router_kernel<<<NTOK / 64, 256, 0, stream>>>(x, gw, out, cnt, psum, ids, prw);
  finalize_kernel<<<1, 64, 0, stream>>>(cnt, psum, base, out);
  gather_kernel<<<dim3(NTOK / 64, NEXP), 256, 0, stream>>>(x, xg, cnt, base, ids);
  tconv_all_kernel<<<8192, 256, 0, stream>>>(w1, w1t, w2, w2t);
  moe_gemm_kernel<0><<<NEXP * 32 * (HDIM / 256), 512, 0, stream>>>(
      xg, w1t, hbuf, nullptr, cnt, base, ids, prw);
  moe_gemm_kernel<1><<<NEXP * 32 * (DDIM / 256), 512, 0, stream>>>(
      hbuf, w2t, nullptr, out + OFF_OUT, cnt, base, ids, prw);
}

// Round 16
// 320.919 us; speedup vs baseline: 1.2206x; 1.2206x over previous
//
#include <hip/hip_runtime.h>
#include <hip/hip_bf16.h>
#include <cstdint>

typedef unsigned short u16;
typedef unsigned int u32;
typedef short s16x8 __attribute__((ext_vector_type(8)));
typedef float f32x4 __attribute__((ext_vector_type(4)));

// Problem constants (B=4, T=2048, D=1024, E=8, H=2048, K=2)
constexpr int NTOK = 8192;
constexpr int DDIM = 1024;
constexpr int NEXP = 8;
constexpr int HDIM = 2048;
constexpr int NPAIR = NTOK * 2;   // 16384

// d_out layout (floats), concatenated tuple
constexpr size_t OFF_OUT   = 0;
constexpr size_t OFF_AUX   = 8388608;
constexpr size_t OFF_PROBS = 8388609;
constexpr size_t OFF_TIDX  = 8454145;
constexpr size_t OFF_TPR   = 8470529;

// workspace layout (bytes)
constexpr size_t WS_CNT  = 0;          // 8 int
constexpr size_t WS_PSUM = 32;         // 8 float
constexpr size_t WS_IDS  = 1024;       // 8*8192 int   -> ends 263168
constexpr size_t WS_PRW  = 263168;     // 8*8192 float -> ends 525312
constexpr size_t WS_W1T  = 17302528;   // 8*2048*1024 bf16 (transposed [E][H][D])
constexpr size_t WS_W2T  = 50856960;   // 8*1024*2048 bf16 (transposed [E][D][H])
constexpr size_t WS_H    = 84411392;   // 16384*2048 bf16
constexpr size_t WS_XG   = 151520256;  // 16384*1024 bf16 (gathered A rows)
constexpr size_t WS_NEED = 185074688;

__device__ __forceinline__ u16 f2b(float f) {
  u32 u = __float_as_uint(f);
  u32 r = (u + 0x7fffu + ((u >> 16) & 1u)) >> 16;
  return (u16)r;
}

typedef const uint32_t __attribute__((address_space(1)))* gptr_t;
typedef uint32_t __attribute__((address_space(3)))* lptr_t;

__device__ __forceinline__ void gload16(const void* gp, void* lp) {
  __builtin_amdgcn_global_load_lds((gptr_t)gp, (lptr_t)(uintptr_t)lp, 16, 0, 0);
}

// ============ PREP: router (blocks 0..127) + weight transposes (blocks 128..8319) ============
// Router is only 128 blocks; running it standalone idles >half the GPU. Fused, it
// hides entirely under the 8192 memory-bound tconv blocks.
__global__ __launch_bounds__(256) void prep_kernel(
    const float* __restrict__ x, const float* __restrict__ gw,
    float* __restrict__ outbuf,
    int* __restrict__ cnt, float* __restrict__ psum,
    int* __restrict__ ids, float* __restrict__ prw,
    const float* __restrict__ w1, u16* __restrict__ w1t,
    const float* __restrict__ w2, u16* __restrict__ w2t) {
  __shared__ float smem[DDIM * NEXP];  // 32 KB: router gate staging / tconv tile
  __shared__ int lcnt[NEXP];
  __shared__ float psl[NEXP];
  __shared__ int gbl[NEXP];

  const int bid = blockIdx.x;
  const int tid = threadIdx.x;

  if (bid >= 128) {
    // ---------------- tconv role ----------------
    int id = bid - 128;
    const float* in;
    u16* out;
    int R, C, e, r;
    if (id < 4096) {
      in = w1; out = w1t; R = DDIM; C = HDIM;
      e = id >> 9; r = id & 511;
    } else {
      id -= 4096;
      in = w2; out = w2t; R = HDIM; C = DDIM;
      e = id >> 9; r = id & 511;
    }
    int xt = (R == DDIM) ? (r & 31) : (r & 15);
    int yt = (R == DDIM) ? (r >> 5) : (r >> 4);
    int c0 = xt * 64, r0 = yt * 64;

    float (*tile)[65] = (float(*)[65])smem;
    int tx = tid & 15, ty = tid >> 4;
    const float* src = in + (size_t)e * R * C;
#pragma unroll
    for (int i = 0; i < 4; ++i) {
      int rr = ty + i * 16;
      float4 v = *(const float4*)(src + (size_t)(r0 + rr) * C + c0 + tx * 4);
      tile[rr][tx * 4 + 0] = v.x; tile[rr][tx * 4 + 1] = v.y;
      tile[rr][tx * 4 + 2] = v.z; tile[rr][tx * 4 + 3] = v.w;
    }
    __syncthreads();
    u16* dst = out + (size_t)e * R * C;
#pragma unroll
    for (int i = 0; i < 4; ++i) {
      int c = ty + i * 16;
      ushort4 o;
      o.x = f2b(tile[tx * 4 + 0][c]); o.y = f2b(tile[tx * 4 + 1][c]);
      o.z = f2b(tile[tx * 4 + 2][c]); o.w = f2b(tile[tx * 4 + 3][c]);
      *(ushort4*)(dst + (size_t)(c0 + c) * R + r0 + tx * 4) = o;
    }
    return;
  }

  // ---------------- router role ----------------
#pragma unroll
  for (int k = 0; k < 8; ++k)
    ((float4*)smem)[tid + k * 256] = ((const float4*)gw)[tid + k * 256];
  if (tid < NEXP) { lcnt[tid] = 0; psl[tid] = 0.f; }
  __syncthreads();

  const int tloc = tid >> 2, part = tid & 3;
  const int t = bid * 64 + tloc;
  double acc[NEXP];
#pragma unroll
  for (int e = 0; e < NEXP; ++e) acc[e] = 0.0;

  const float* xrow = x + (size_t)t * DDIM + part * 256;
  for (int i = 0; i < 64; ++i) {
    float4 v = ((const float4*)xrow)[i];
    const float* g = &smem[(part * 256 + i * 4) * NEXP];
#pragma unroll
    for (int j = 0; j < 4; ++j) {
      double xs = (double)((const float*)&v)[j];
#pragma unroll
      for (int e = 0; e < NEXP; ++e) acc[e] += xs * (double)g[j * NEXP + e];
    }
  }
#pragma unroll
  for (int e = 0; e < NEXP; ++e) {
    acc[e] += __shfl_xor(acc[e], 1);
    acc[e] += __shfl_xor(acc[e], 2);
  }

  int e0 = 0, e1 = 0, lp0 = 0, lp1 = 0;
  float tp0 = 0.f, tp1 = 0.f;
  if (part == 0) {
    float l[NEXP];
#pragma unroll
    for (int e = 0; e < NEXP; ++e) l[e] = (float)acc[e];
    float m = l[0];
#pragma unroll
    for (int e = 1; e < NEXP; ++e) m = fmaxf(m, l[e]);
    float p[NEXP], s = 0.f;
#pragma unroll
    for (int e = 0; e < NEXP; ++e) { p[e] = expf(l[e] - m); s += p[e]; }
    float inv = 1.0f / s;
#pragma unroll
    for (int e = 0; e < NEXP; ++e) {
      p[e] *= inv;
      outbuf[OFF_PROBS + (size_t)t * NEXP + e] = p[e];
      atomicAdd(&psl[e], p[e]);
    }
#pragma unroll
    for (int e = 1; e < NEXP; ++e) if (p[e] > p[e0]) e0 = e;
    e1 = -1;
#pragma unroll
    for (int e = 0; e < NEXP; ++e)
      if (e != e0 && (e1 < 0 || p[e] > p[e1])) e1 = e;
    float ps = p[e0] + p[e1];
    tp0 = p[e0] / ps;
    tp1 = p[e1] / ps;
    outbuf[OFF_TIDX + t * 2 + 0] = (float)e0;
    outbuf[OFF_TIDX + t * 2 + 1] = (float)e1;
    outbuf[OFF_TPR + t * 2 + 0] = tp0;
    outbuf[OFF_TPR + t * 2 + 1] = tp1;
    lp0 = atomicAdd(&lcnt[e0], 1);
    lp1 = atomicAdd(&lcnt[e1], 1);
  }
  __syncthreads();
  if (tid < NEXP) {
    gbl[tid] = atomicAdd(&cnt[tid], lcnt[tid]);
    atomicAdd(&psum[tid], psl[tid]);
  }
  __syncthreads();
  if (part == 0) {
    int pos0 = gbl[e0] + lp0;
    int pos1 = gbl[e1] + lp1;
    ids[e0 * NTOK + pos0] = t;
    ids[e1 * NTOK + pos1] = t;
    prw[e0 * NTOK + pos0] = tp0;
    prw[e1 * NTOK + pos1] = tp1;
  }
}

// ------- gather + convert + aux: xg[base[e]+pos] = bf16(x[ids[e][pos]]) -------
// base computed inline from cnt (finalize kernel eliminated); block (0,0) writes aux.
__global__ __launch_bounds__(256) void gather_kernel(
    const float* __restrict__ x, u16* __restrict__ xg,
    const int* __restrict__ cnt, const float* __restrict__ psum,
    const int* __restrict__ ids, float* __restrict__ outbuf) {
  const int e = blockIdx.y;
  int cn[NEXP];
#pragma unroll
  for (int i = 0; i < NEXP; ++i) cn[i] = cnt[i];
  int gb = 0;
#pragma unroll
  for (int i = 0; i < NEXP; ++i) if (i < e) gb += cn[i];
  const int cnte = cn[e];

  if (blockIdx.x == 0 && blockIdx.y == 0 && threadIdx.x == 0) {
    float aux = 0.f;
#pragma unroll
    for (int i = 0; i < NEXP; ++i) aux += (float)cn[i] * psum[i];
    outbuf[OFF_AUX] = aux * (float)NEXP / ((float)NTOK * (float)NTOK);
  }

  const int lane = threadIdx.x & 31;
  const int rgrp = threadIdx.x >> 5;
#pragma unroll
  for (int p = 0; p < 8; ++p) {
    int pos = blockIdx.x * 64 + p * 8 + rgrp;
    if (pos < cnte) {
      int tok = ids[e * NTOK + pos];
      const float4* src = (const float4*)(x + (size_t)tok * DDIM);
      ushort4* dst = (ushort4*)(xg + (size_t)(gb + pos) * DDIM);
#pragma unroll
      for (int pp = 0; pp < 8; ++pp) {
        float4 v = src[pp * 32 + lane];
        ushort4 o;
        o.x = f2b(v.x); o.y = f2b(v.y); o.z = f2b(v.z); o.w = f2b(v.w);
        dst[pp * 32 + lane] = o;
      }
    }
  }
}

// -------- grouped GEMM: 128x128, BK=32, 3-ring one-barrier, supertile (R13-proven) --------
// 1-D grid: e = wgid%8 (XCD affinity). Supertile q -> (mg, nI, mI), m-inner, MGRP=4.
// Ring: vmcnt(4) [tile kt landed; kt+1 in flight] -> barrier [also: compute(kt-1)
// done -> buf (kt+2)%3 free] -> STAGE(kt+2) -> compute(kt).
// MODE 0: A = xg rows [*,1024], B = w1t [E][2048][1024], C = h (bf16, gelu)
// MODE 1: A = h rows  [*,2048], B = w2t [E][1024][2048], out[tok] += prob*v (atomic)
template <int MODE>
__global__ __launch_bounds__(256, 3) void moe_gemm_kernel(
    const u16* __restrict__ Asrc, const u16* __restrict__ Bt,
    u16* __restrict__ hout, float* __restrict__ yout,
    const int* __restrict__ cnt,
    const int* __restrict__ ids, const float* __restrict__ prw) {
  constexpr int KDIM = (MODE == 0) ? 1024 : 2048;
  constexpr int NDIM = (MODE == 0) ? 2048 : 1024;
  constexpr int NT = KDIM / 32;
  constexpr int NB = NDIM / 128;   // n-blocks per expert
  constexpr int MGRP = 4;          // m-blocks per L2 supertile group
  constexpr int QPG = MGRP * NB;   // q's per group
  const int wgid = blockIdx.x;
  const int e = wgid & 7;          // expert -> XCD lane
  const int q = wgid >> 3;
  const int mg = q / QPG;
  const int r = q % QPG;
  const int m0 = (mg * MGRP + (r % MGRP)) * 128;
  const int n0 = (r / MGRP) * 128;

  int cn[NEXP];
#pragma unroll
  for (int i = 0; i < NEXP; ++i) cn[i] = cnt[i];
  const int cnte = cn[e];
  if (m0 >= cnte) return;
  int gbase = 0;
#pragma unroll
  for (int i = 0; i < NEXP; ++i) if (i < e) gbase += cn[i];

  __shared__ u16 Al[3][128 * 32];  // 24 KB
  __shared__ u16 Bl[3][128 * 32];  // 24 KB

  const int tid = threadIdx.x;
  const int lane = tid & 63, wid = tid >> 6;
  const int wm = (wid >> 1) * 64, wn = (wid & 1) * 64;
  const int r15 = lane & 15, l4 = lane >> 4;

  // staging precompute: per qq, LDS slot j=qq*256+tid -> row=j>>2, chunk cp=j&3,
  // holds global chunk c = cp ^ ((row>>1)&3)  (both-sides XOR swizzle)
  const char* aptr[2];
  const char* bptr[2];
#pragma unroll
  for (int qq = 0; qq < 2; ++qq) {
    int j = qq * 256 + tid;
    int row = j >> 2;
    int c = (j & 3) ^ ((row >> 1) & 3);
    int gr = gbase + m0 + row;
    if (gr > NPAIR - 1) gr = NPAIR - 1;
    size_t rowoff = (size_t)gr * KDIM;
    aptr[qq] = (const char*)Asrc + (rowoff + (size_t)c * 8) * 2;
    size_t nrow = (size_t)e * NDIM + n0 + row;
    bptr[qq] = (const char*)Bt + (nrow * KDIM + (size_t)c * 8) * 2;
  }

  f32x4 acc[4][4];
#pragma unroll
  for (int i = 0; i < 4; ++i)
#pragma unroll
    for (int jn = 0; jn < 4; ++jn) acc[i][jn] = (f32x4){0.f, 0.f, 0.f, 0.f};

#define STAGE(b_, kt_)                                                         \
  do {                                                                         \
    const size_t kofs_ = (size_t)(kt_) * 64;  /* bytes: 32 bf16 */             \
    _Pragma("unroll") for (int qq = 0; qq < 2; ++qq) {                         \
      gload16(aptr[qq] + kofs_, (void*)&Al[b_][(size_t)(qq * 256 + tid) * 8]); \
      gload16(bptr[qq] + kofs_, (void*)&Bl[b_][(size_t)(qq * 256 + tid) * 8]); \
    }                                                                          \
  } while (0)

  auto compute = [&](int b) {
    const s16x8* Av = (const s16x8*)Al[b];
    const s16x8* Bv = (const s16x8*)Bl[b];
    s16x8 af[4], bfr[4];
#pragma unroll
    for (int mi = 0; mi < 4; ++mi) {
      int row = wm + mi * 16 + r15;
      af[mi] = Av[row * 4 + (l4 ^ ((row >> 1) & 3))];
    }
#pragma unroll
    for (int ni = 0; ni < 4; ++ni) {
      int row = wn + ni * 16 + r15;
      bfr[ni] = Bv[row * 4 + (l4 ^ ((row >> 1) & 3))];
    }
#pragma unroll
    for (int mi = 0; mi < 4; ++mi)
#pragma unroll
      for (int ni = 0; ni < 4; ++ni)
        acc[mi][ni] = __builtin_amdgcn_mfma_f32_16x16x32_bf16(
            af[mi], bfr[ni], acc[mi][ni], 0, 0, 0);
  };

  // prologue: tiles 0,1 staged into bufs 0,1 (8 loads/thread outstanding)
  STAGE(0, 0);
  STAGE(1, 1);

  int b0 = 0;
  for (int kt = 0; kt < NT; ++kt) {
    if (kt < NT - 1)
      asm volatile("s_waitcnt vmcnt(4)" ::: "memory");  // tile kt landed, kt+1 in flight
    else
      asm volatile("s_waitcnt vmcnt(0)" ::: "memory");  // last tile: drain
    __builtin_amdgcn_s_barrier();  // all waves: tile kt ready AND compute(kt-1) done
    asm volatile("" ::: "memory");
    if (kt + 2 < NT) {
      int bs = b0 + 2; if (bs >= 3) bs -= 3;
      STAGE(bs, kt + 2);  // into buffer freed by compute(kt-1)
    }
    compute(b0);
    if (++b0 == 3) b0 = 0;
  }
#undef STAGE

  // epilogue: C/D layout col = lane&15, row = (lane>>4)*4 + j
#pragma unroll
  for (int mi = 0; mi < 4; ++mi) {
#pragma unroll
    for (int jr = 0; jr < 4; ++jr) {
      int rl = wm + mi * 16 + l4 * 4 + jr;
      if (m0 + rl < cnte) {
        if (MODE == 0) {
          size_t grow = (size_t)(gbase + m0 + rl);
#pragma unroll
          for (int ni = 0; ni < 4; ++ni) {
            float v = acc[mi][ni][jr];
            v = 0.5f * v * (1.0f + erff(v * 0.70710678118654752f));
            int col = n0 + wn + ni * 16 + r15;
            hout[grow * NDIM + col] = f2b(v);
          }
        } else {
          int tok = ids[e * NTOK + m0 + rl];
          float p = prw[e * NTOK + m0 + rl];
#pragma unroll
          for (int ni = 0; ni < 4; ++ni) {
            int col = n0 + wn + ni * 16 + r15;
            atomicAdd(&yout[(size_t)tok * DDIM + col], p * acc[mi][ni][jr]);
          }
        }
      }
    }
  }
}

extern "C" void kernel_launch(void* const* d_in, const int* in_sizes, int n_in,
                              void* d_out, int out_size, void* d_ws, size_t ws_size,
                              hipStream_t stream) {
  const float* x = (const float*)d_in[0];
  const float* gw = (const float*)d_in[1];
  const float* w1 = (const float*)d_in[2];
  const float* w2 = (const float*)d_in[3];
  float* out = (float*)d_out;
  char* w = (char*)d_ws;
  if (ws_size < WS_NEED) return;  // insufficient workspace -> loud failure

  int* cnt = (int*)(w + WS_CNT);
  float* psum = (float*)(w + WS_PSUM);
  int* ids = (int*)(w + WS_IDS);
  float* prw = (float*)(w + WS_PRW);
  u16* w1t = (u16*)(w + WS_W1T);
  u16* w2t = (u16*)(w + WS_W2T);
  u16* hbuf = (u16*)(w + WS_H);
  u16* xg = (u16*)(w + WS_XG);

  (void)hipMemsetAsync(w, 0, 96, stream);
  (void)hipMemsetAsync(out + OFF_OUT, 0, (size_t)NTOK * DDIM * sizeof(float), stream);
  // fused: router (blocks 0..127) + both weight transposes (blocks 128..8319)
  prep_kernel<<<128 + 8192, 256, 0, stream>>>(x, gw, out, cnt, psum, ids, prw,
                                              w1, w1t, w2, w2t);
  // gather (computes base inline) + aux-loss write
  gather_kernel<<<dim3(NTOK / 64, NEXP), 256, 0, stream>>>(x, xg, cnt, psum, ids, out);
  moe_gemm_kernel<0><<<NEXP * 64 * (HDIM / 128), 256, 0, stream>>>(
      xg, w1t, hbuf, nullptr, cnt, ids, prw);
  moe_gemm_kernel<1><<<NEXP * 64 * (DDIM / 128), 256, 0, stream>>>(
      hbuf, w2t, nullptr, out + OFF_OUT, cnt, ids, prw);
}